// Round 1
// baseline (1253.005 us; speedup 1.0000x reference)
//
#include <hip/hip_runtime.h>
#include <math.h>

// ---------------------------------------------------------------------------
// AGDN: 2 layers of  h0 = x@W^T ; f_{k+1} = scatter_add(f_k[src] -> dst) (K=3)
//       score_k = lrelu(h0.att_lo + f_k.att_hi); softmax over k=0..3
//       out = sum_k attn_k * f_k + res + bias  (layer1: res = x@resW^T, +ELU;
//                                               layer2: res = h0)
// ---------------------------------------------------------------------------

#define NPB 32   // nodes per block tile in the GEMM

template<int KDIM, bool HAS_RES>
__global__ __launch_bounds__(256)
void gemm_kernel(const float* __restrict__ x,     // [n, KDIM]
                 const float* __restrict__ W,     // [64, KDIM]
                 const float* __restrict__ Wres,  // [64, KDIM] or null
                 float* __restrict__ y,           // [n, 64]
                 float* __restrict__ yres,        // [n, 64] or null
                 int n)
{
    constexpr int PAD = KDIM + 1;                 // break stride-128 bank conflict
    __shared__ float xs[NPB * PAD];
    __shared__ float wsh[64 * PAD];
    __shared__ float wrsh[HAS_RES ? 64 * PAD : 1];

    const int tid = threadIdx.x;
    for (int i = tid; i < 64 * KDIM; i += 256) {
        int r = i / KDIM, c = i % KDIM;
        wsh[r * PAD + c] = W[i];
        if constexpr (HAS_RES) wrsh[r * PAD + c] = Wres[i];
    }
    const int node0 = blockIdx.x * NPB;
    for (int i = tid; i < NPB * KDIM; i += 256) {
        int r = i / KDIM, c = i % KDIM;
        int nn = node0 + r;
        xs[r * PAD + c] = (nn < n) ? x[(size_t)nn * KDIM + c] : 0.f;
    }
    __syncthreads();

    const int og = (tid & 15) * 4;   // 16 groups x 4 outputs = 64
    const int ng = (tid >> 4) * 2;   // 16 groups x 2 nodes  = 32

    float acc[2][4] = {};
    float accr[2][4] = {};
    for (int k = 0; k < KDIM; ++k) {
        float xv0 = xs[ng * PAD + k];
        float xv1 = xs[(ng + 1) * PAD + k];
        #pragma unroll
        for (int j = 0; j < 4; ++j) {
            float w = wsh[(og + j) * PAD + k];
            acc[0][j] += xv0 * w;
            acc[1][j] += xv1 * w;
        }
        if constexpr (HAS_RES) {
            #pragma unroll
            for (int j = 0; j < 4; ++j) {
                float w = wrsh[(og + j) * PAD + k];
                accr[0][j] += xv0 * w;
                accr[1][j] += xv1 * w;
            }
        }
    }
    #pragma unroll
    for (int i = 0; i < 2; ++i) {
        int nn = node0 + ng + i;
        if (nn < n) {
            *(float4*)&y[(size_t)nn * 64 + og] =
                make_float4(acc[i][0], acc[i][1], acc[i][2], acc[i][3]);
            if constexpr (HAS_RES) {
                *(float4*)&yres[(size_t)nn * 64 + og] =
                    make_float4(accr[i][0], accr[i][1], accr[i][2], accr[i][3]);
            }
        }
    }
}

// One wave per edge: lane = feature. Gather = contiguous 256B row; scatter via
// 64 coalesced f32 atomics onto the dst row.
__global__ __launch_bounds__(256)
void hop_kernel(const float* __restrict__ fin, float* __restrict__ fout,
                const int* __restrict__ src, const int* __restrict__ dst, int E)
{
    int e = blockIdx.x * 4 + (threadIdx.x >> 6);
    if (e >= E) return;
    int lane = threadIdx.x & 63;
    int s = src[e], d = dst[e];
    float v = fin[(size_t)s * 64 + lane];
    atomicAdd(&fout[(size_t)d * 64 + lane], v);
}

// MODE 0: layer 1 (res from res buffer, apply ELU)
// MODE 1: layer 2 (res = h0, no ELU)
template<int MODE>
__global__ __launch_bounds__(256)
void combine_kernel(const float* __restrict__ h0, const float* __restrict__ f1,
                    const float* __restrict__ f2, const float* __restrict__ f3,
                    const float* __restrict__ res, const float* __restrict__ att,
                    const float* __restrict__ bias, float* __restrict__ out, int n)
{
    int node = blockIdx.x * 4 + (threadIdx.x >> 6);
    if (node >= n) return;
    int lane = threadIdx.x & 63;
    size_t base = (size_t)node * 64 + lane;

    float v0 = h0[base], v1 = f1[base], v2 = f2[base], v3 = f3[base];
    float alo = att[lane], ahi = att[64 + lane];

    float p0 = v0 * alo;                    // shared h0 . att_lo term
    float q0 = v0 * ahi;                    // f_k . att_hi terms (f_0 = h0)
    float q1 = v1 * ahi;
    float q2 = v2 * ahi;
    float q3 = v3 * ahi;
    #pragma unroll
    for (int off = 32; off > 0; off >>= 1) {
        p0 += __shfl_xor(p0, off);
        q0 += __shfl_xor(q0, off);
        q1 += __shfl_xor(q1, off);
        q2 += __shfl_xor(q2, off);
        q3 += __shfl_xor(q3, off);
    }
    float s0 = p0 + q0, s1 = p0 + q1, s2 = p0 + q2, s3 = p0 + q3;
    s0 = s0 > 0.f ? s0 : 0.2f * s0;
    s1 = s1 > 0.f ? s1 : 0.2f * s1;
    s2 = s2 > 0.f ? s2 : 0.2f * s2;
    s3 = s3 > 0.f ? s3 : 0.2f * s3;
    float m = fmaxf(fmaxf(s0, s1), fmaxf(s2, s3));
    float e0 = expf(s0 - m), e1 = expf(s1 - m), e2 = expf(s2 - m), e3 = expf(s3 - m);
    float inv = 1.f / (e0 + e1 + e2 + e3);
    float o = (e0 * v0 + e1 * v1 + e2 * v2 + e3 * v3) * inv;

    float r = (MODE == 0) ? res[base] : v0;
    o += r + bias[lane];
    if (MODE == 0) o = o > 0.f ? o : expm1f(o);   // ELU(alpha=1)
    out[base] = o;
}

extern "C" void kernel_launch(void* const* d_in, const int* in_sizes, int n_in,
                              void* d_out, int out_size, void* d_ws, size_t ws_size,
                              hipStream_t stream)
{
    const float* x     = (const float*)d_in[0];
    const int*   ei    = (const int*)  d_in[1];
    const float* W1    = (const float*)d_in[2];
    const float* att1  = (const float*)d_in[3];
    const float* bias1 = (const float*)d_in[4];
    const float* resW1 = (const float*)d_in[5];
    const float* W2    = (const float*)d_in[6];
    const float* att2  = (const float*)d_in[7];
    const float* bias2 = (const float*)d_in[8];

    const int N_ = in_sizes[0] / 128;
    const int E_ = in_sizes[1] / 2;
    const int* src = ei;
    const int* dst = ei + E_;

    float* out = (float*)d_out;
    size_t S = (size_t)N_ * 64;
    float* h0 = (float*)d_ws;
    float* f1 = h0 + S;
    float* f2 = f1 + S;
    float* f3 = f2 + S;

    dim3 blk(256);
    int gemm_grid = (N_ + NPB - 1) / NPB;
    int hop_grid  = (E_ + 3) / 4;
    int node_grid = (N_ + 3) / 4;

    // ---------------- layer 1 ----------------
    // h0 = x@W1^T ; res (in d_out) = x@resW1^T
    gemm_kernel<128, true><<<gemm_grid, blk, 0, stream>>>(x, W1, resW1, h0, out, N_);

    hipMemsetAsync(f1, 0, S * sizeof(float), stream);
    hop_kernel<<<hop_grid, blk, 0, stream>>>(h0, f1, src, dst, E_);
    hipMemsetAsync(f2, 0, S * sizeof(float), stream);
    hop_kernel<<<hop_grid, blk, 0, stream>>>(f1, f2, src, dst, E_);
    hipMemsetAsync(f3, 0, S * sizeof(float), stream);
    hop_kernel<<<hop_grid, blk, 0, stream>>>(f2, f3, src, dst, E_);

    // h (layer-1 output) -> d_out  (reads res from d_out at the same index)
    combine_kernel<0><<<node_grid, blk, 0, stream>>>(h0, f1, f2, f3, out, att1, bias1, out, N_);

    // ---------------- layer 2 ----------------
    // h0 = h@W2^T  (h lives in d_out)
    gemm_kernel<64, false><<<gemm_grid, blk, 0, stream>>>(out, W2, nullptr, h0, nullptr, N_);

    hipMemsetAsync(f1, 0, S * sizeof(float), stream);
    hop_kernel<<<hop_grid, blk, 0, stream>>>(h0, f1, src, dst, E_);
    hipMemsetAsync(f2, 0, S * sizeof(float), stream);
    hop_kernel<<<hop_grid, blk, 0, stream>>>(f1, f2, src, dst, E_);
    hipMemsetAsync(f3, 0, S * sizeof(float), stream);
    hop_kernel<<<hop_grid, blk, 0, stream>>>(f2, f3, src, dst, E_);

    combine_kernel<1><<<node_grid, blk, 0, stream>>>(h0, f1, f2, f3, nullptr, att2, bias2, out, N_);
}

// Round 2
// 543.080 us; speedup vs baseline: 2.3072x; 2.3072x over previous
//
#include <hip/hip_runtime.h>
#include <math.h>

// ---------------------------------------------------------------------------
// AGDN via CSR-gather (no float atomics):
//   build CSR by dst once; each hop = wave-per-node gather-sum over in-edges.
//   3rd hop of each layer fused with the attention-softmax combine.
// ---------------------------------------------------------------------------

#define NPB 32   // nodes per block tile in the GEMM

template<int KDIM, bool HAS_RES>
__global__ __launch_bounds__(256)
void gemm_kernel(const float* __restrict__ x,     // [n, KDIM]
                 const float* __restrict__ W,     // [64, KDIM]
                 const float* __restrict__ Wres,  // [64, KDIM] or null
                 float* __restrict__ y,           // [n, 64]
                 float* __restrict__ yres,        // [n, 64] or null
                 int n)
{
    constexpr int PAD = KDIM + 1;                 // break stride-128 bank conflict
    __shared__ float xs[NPB * PAD];
    __shared__ float wsh[64 * PAD];
    __shared__ float wrsh[HAS_RES ? 64 * PAD : 1];

    const int tid = threadIdx.x;
    for (int i = tid; i < 64 * KDIM; i += 256) {
        int r = i / KDIM, c = i % KDIM;
        wsh[r * PAD + c] = W[i];
        if constexpr (HAS_RES) wrsh[r * PAD + c] = Wres[i];
    }
    const int node0 = blockIdx.x * NPB;
    for (int i = tid; i < NPB * KDIM; i += 256) {
        int r = i / KDIM, c = i % KDIM;
        int nn = node0 + r;
        xs[r * PAD + c] = (nn < n) ? x[(size_t)nn * KDIM + c] : 0.f;
    }
    __syncthreads();

    const int og = (tid & 15) * 4;   // 16 groups x 4 outputs = 64
    const int ng = (tid >> 4) * 2;   // 16 groups x 2 nodes  = 32

    float acc[2][4] = {};
    float accr[2][4] = {};
    for (int k = 0; k < KDIM; ++k) {
        float xv0 = xs[ng * PAD + k];
        float xv1 = xs[(ng + 1) * PAD + k];
        #pragma unroll
        for (int j = 0; j < 4; ++j) {
            float w = wsh[(og + j) * PAD + k];
            acc[0][j] += xv0 * w;
            acc[1][j] += xv1 * w;
        }
        if constexpr (HAS_RES) {
            #pragma unroll
            for (int j = 0; j < 4; ++j) {
                float w = wrsh[(og + j) * PAD + k];
                accr[0][j] += xv0 * w;
                accr[1][j] += xv1 * w;
            }
        }
    }
    #pragma unroll
    for (int i = 0; i < 2; ++i) {
        int nn = node0 + ng + i;
        if (nn < n) {
            *(float4*)&y[(size_t)nn * 64 + og] =
                make_float4(acc[i][0], acc[i][1], acc[i][2], acc[i][3]);
            if constexpr (HAS_RES) {
                *(float4*)&yres[(size_t)nn * 64 + og] =
                    make_float4(accr[i][0], accr[i][1], accr[i][2], accr[i][3]);
            }
        }
    }
}

// ---------------- CSR build ----------------
__global__ __launch_bounds__(256)
void hist_kernel(const int* __restrict__ dst, int* __restrict__ cnt, int E)
{
    int e = blockIdx.x * 256 + threadIdx.x;
    if (e < E) atomicAdd(&cnt[dst[e]], 1);
}

__global__ __launch_bounds__(256)
void scanA_kernel(const int* __restrict__ cnt, int* __restrict__ excl,
                  int* __restrict__ bsum, int n)
{
    __shared__ int sh[256];
    int i = blockIdx.x * 256 + threadIdx.x;
    int v = (i < n) ? cnt[i] : 0;
    sh[threadIdx.x] = v;
    __syncthreads();
    #pragma unroll
    for (int off = 1; off < 256; off <<= 1) {
        int t = (threadIdx.x >= off) ? sh[threadIdx.x - off] : 0;
        __syncthreads();
        sh[threadIdx.x] += t;
        __syncthreads();
    }
    if (i < n) excl[i] = sh[threadIdx.x] - v;
    if (threadIdx.x == 255) bsum[blockIdx.x] = sh[255];
}

__global__ __launch_bounds__(256)
void scanB_kernel(const int* __restrict__ bsum, int* __restrict__ bofs, int nb)
{
    __shared__ int sh[256];
    int v = (threadIdx.x < nb) ? bsum[threadIdx.x] : 0;
    sh[threadIdx.x] = v;
    __syncthreads();
    #pragma unroll
    for (int off = 1; off < 256; off <<= 1) {
        int t = (threadIdx.x >= off) ? sh[threadIdx.x - off] : 0;
        __syncthreads();
        sh[threadIdx.x] += t;
        __syncthreads();
    }
    if (threadIdx.x < nb) bofs[threadIdx.x] = sh[threadIdx.x] - v;
}

__global__ __launch_bounds__(256)
void scanC_kernel(const int* __restrict__ excl, const int* __restrict__ bofs,
                  int* __restrict__ rowptr, int* __restrict__ cur, int n, int E)
{
    int i = blockIdx.x * 256 + threadIdx.x;
    if (i < n) {
        int v = excl[i] + bofs[i >> 8];
        rowptr[i] = v;
        cur[i] = v;
    }
    if (i == n) rowptr[n] = E;
}

__global__ __launch_bounds__(256)
void scatter_kernel(const int* __restrict__ src, const int* __restrict__ dst,
                    int* __restrict__ cur, int* __restrict__ col, int E)
{
    int e = blockIdx.x * 256 + threadIdx.x;
    if (e < E) {
        int p = atomicAdd(&cur[dst[e]], 1);
        col[p] = src[e];
    }
}

// ---------------- hop: wave per node, lane = feature ----------------
__global__ __launch_bounds__(256)
void hop_csr_kernel(const float* __restrict__ fin, float* __restrict__ fout,
                    const int* __restrict__ rowptr, const int* __restrict__ col, int n)
{
    int node = blockIdx.x * 4 + (threadIdx.x >> 6);
    if (node >= n) return;
    int lane = threadIdx.x & 63;
    int beg = rowptr[node], end = rowptr[node + 1];
    float a0 = 0.f, a1 = 0.f;
    int i = beg;
    for (; i + 2 <= end; i += 2) {
        int s0 = col[i], s1 = col[i + 1];
        a0 += fin[(size_t)s0 * 64 + lane];
        a1 += fin[(size_t)s1 * 64 + lane];
    }
    if (i < end) a0 += fin[(size_t)col[i] * 64 + lane];
    fout[(size_t)node * 64 + lane] = a0 + a1;
}

// ---------------- 3rd hop fused with attention combine ----------------
// MODE 0: layer 1 (res from res buffer, apply ELU)
// MODE 1: layer 2 (res = h0, no ELU)
template<int MODE>
__global__ __launch_bounds__(256)
void hop3_combine_kernel(const float* __restrict__ h0, const float* __restrict__ f1,
                         const float* __restrict__ f2,
                         const float* __restrict__ res, const float* __restrict__ att,
                         const float* __restrict__ bias, float* __restrict__ out,
                         const int* __restrict__ rowptr, const int* __restrict__ col, int n)
{
    int node = blockIdx.x * 4 + (threadIdx.x >> 6);
    if (node >= n) return;
    int lane = threadIdx.x & 63;
    size_t base = (size_t)node * 64 + lane;

    // f3 = gather-sum of f2 rows
    int beg = rowptr[node], end = rowptr[node + 1];
    float a0 = 0.f, a1 = 0.f;
    int i = beg;
    for (; i + 2 <= end; i += 2) {
        int s0 = col[i], s1 = col[i + 1];
        a0 += f2[(size_t)s0 * 64 + lane];
        a1 += f2[(size_t)s1 * 64 + lane];
    }
    if (i < end) a0 += f2[(size_t)col[i] * 64 + lane];
    float v3 = a0 + a1;

    float v0 = h0[base], v1 = f1[base], v2 = f2[base];
    float alo = att[lane], ahi = att[64 + lane];

    float p0 = v0 * alo;                    // shared h0 . att_lo term
    float q0 = v0 * ahi;
    float q1 = v1 * ahi;
    float q2 = v2 * ahi;
    float q3 = v3 * ahi;
    #pragma unroll
    for (int off = 32; off > 0; off >>= 1) {
        p0 += __shfl_xor(p0, off);
        q0 += __shfl_xor(q0, off);
        q1 += __shfl_xor(q1, off);
        q2 += __shfl_xor(q2, off);
        q3 += __shfl_xor(q3, off);
    }
    float s0 = p0 + q0, s1 = p0 + q1, s2 = p0 + q2, s3 = p0 + q3;
    s0 = s0 > 0.f ? s0 : 0.2f * s0;
    s1 = s1 > 0.f ? s1 : 0.2f * s1;
    s2 = s2 > 0.f ? s2 : 0.2f * s2;
    s3 = s3 > 0.f ? s3 : 0.2f * s3;
    float m = fmaxf(fmaxf(s0, s1), fmaxf(s2, s3));
    float e0 = expf(s0 - m), e1 = expf(s1 - m), e2 = expf(s2 - m), e3 = expf(s3 - m);
    float inv = 1.f / (e0 + e1 + e2 + e3);
    float o = (e0 * v0 + e1 * v1 + e2 * v2 + e3 * v3) * inv;

    float r = (MODE == 0) ? res[base] : v0;
    o += r + bias[lane];
    if (MODE == 0) o = o > 0.f ? o : expm1f(o);   // ELU(alpha=1)
    out[base] = o;
}

extern "C" void kernel_launch(void* const* d_in, const int* in_sizes, int n_in,
                              void* d_out, int out_size, void* d_ws, size_t ws_size,
                              hipStream_t stream)
{
    const float* x     = (const float*)d_in[0];
    const int*   ei    = (const int*)  d_in[1];
    const float* W1    = (const float*)d_in[2];
    const float* att1  = (const float*)d_in[3];
    const float* bias1 = (const float*)d_in[4];
    const float* resW1 = (const float*)d_in[5];
    const float* W2    = (const float*)d_in[6];
    const float* att2  = (const float*)d_in[7];
    const float* bias2 = (const float*)d_in[8];

    const int N_ = in_sizes[0] / 128;
    const int E_ = in_sizes[1] / 2;
    const int* src = ei;
    const int* dst = ei + E_;

    float* out = (float*)d_out;
    size_t S = (size_t)N_ * 64;
    float* h0 = (float*)d_ws;
    float* f1 = h0 + S;
    float* f2 = f1 + S;
    int* rowptr = (int*)(f2 + S);        // N+1
    int* cur    = rowptr + (N_ + 1);     // N  (also reused as histogram cnt)
    int* excl   = cur + N_;              // N
    int* bsum   = excl + N_;             // 256
    int* bofs   = bsum + 256;            // 256
    int* col    = bofs + 256;            // E

    dim3 blk(256);
    int gemm_grid = (N_ + NPB - 1) / NPB;
    int node_grid = (N_ + 3) / 4;
    int edge_grid = (E_ + 255) / 256;
    int nb        = (N_ + 255) / 256;    // scan blocks (<=256 required)

    // ---------------- CSR build (by dst) ----------------
    hipMemsetAsync(cur, 0, (size_t)N_ * sizeof(int), stream);
    hist_kernel<<<edge_grid, blk, 0, stream>>>(dst, cur, E_);
    scanA_kernel<<<nb, blk, 0, stream>>>(cur, excl, bsum, N_);
    scanB_kernel<<<1, blk, 0, stream>>>(bsum, bofs, nb);
    scanC_kernel<<<nb + 1, blk, 0, stream>>>(excl, bofs, rowptr, cur, N_, E_);
    scatter_kernel<<<edge_grid, blk, 0, stream>>>(src, dst, cur, col, E_);

    // ---------------- layer 1 ----------------
    gemm_kernel<128, true><<<gemm_grid, blk, 0, stream>>>(x, W1, resW1, h0, out, N_);
    hop_csr_kernel<<<node_grid, blk, 0, stream>>>(h0, f1, rowptr, col, N_);
    hop_csr_kernel<<<node_grid, blk, 0, stream>>>(f1, f2, rowptr, col, N_);
    hop3_combine_kernel<0><<<node_grid, blk, 0, stream>>>(h0, f1, f2, out, att1, bias1, out,
                                                          rowptr, col, N_);

    // ---------------- layer 2 ----------------
    gemm_kernel<64, false><<<gemm_grid, blk, 0, stream>>>(out, W2, nullptr, h0, nullptr, N_);
    hop_csr_kernel<<<node_grid, blk, 0, stream>>>(h0, f1, rowptr, col, N_);
    hop_csr_kernel<<<node_grid, blk, 0, stream>>>(f1, f2, rowptr, col, N_);
    hop3_combine_kernel<1><<<node_grid, blk, 0, stream>>>(h0, f1, f2, nullptr, att2, bias2, out,
                                                          rowptr, col, N_);
}

// Round 3
// 485.382 us; speedup vs baseline: 2.5815x; 1.1189x over previous
//
#include <hip/hip_runtime.h>
#include <math.h>

// ---------------------------------------------------------------------------
// AGDN via CSR-gather (no float atomics):
//   build CSR by dst once; each hop = wave-per-node gather-sum over in-edges.
//   3rd hop of each layer fused with the attention-softmax combine.
// GEMM: LDS = x-tile only (34 KB -> 4 blocks/CU); weights streamed from
//   global (L2-broadcast) as float4 along k; 4 nodes x 8 outputs per thread.
// ---------------------------------------------------------------------------

// J = Dout/16. SPLIT: cols 0..63 -> y (from W), 64..127 -> yres (from Wres).
template<int KDIM, int J, bool SPLIT>
__global__ __launch_bounds__(256)
void gemm_kernel(const float* __restrict__ x,     // [n, KDIM]
                 const float* __restrict__ W,     // [64, KDIM]
                 const float* __restrict__ Wres,  // [64, KDIM] or null
                 float* __restrict__ y,           // [n, 64]
                 float* __restrict__ yres,        // [n, 64] or null
                 int n)
{
    constexpr int PAD = KDIM + 4;                 // keeps float4 align, breaks bank repeat
    __shared__ float xs[64 * PAD];

    const int tid = threadIdx.x;
    const int node0 = blockIdx.x * 64;

    // stage 64-node x tile as float4 (coalesced)
    constexpr int K4 = KDIM / 4;
    for (int i = tid; i < 64 * K4; i += 256) {
        int r = i / K4, c4 = (i % K4) * 4;
        int nn = node0 + r;
        float4 v = (nn < n) ? *(const float4*)&x[(size_t)nn * KDIM + c4]
                            : make_float4(0.f, 0.f, 0.f, 0.f);
        *(float4*)&xs[r * PAD + c4] = v;
    }
    __syncthreads();

    const int o_lane = tid & 15;       // 16 output lanes
    const int ng = (tid >> 4) * 4;     // 16 groups x 4 nodes = 64

    float acc[4][J] = {};
    for (int k4 = 0; k4 < KDIM; k4 += 4) {
        float4 xv[4];
        #pragma unroll
        for (int i = 0; i < 4; ++i)
            xv[i] = *(const float4*)&xs[(ng + i) * PAD + k4];
        #pragma unroll
        for (int j = 0; j < J; ++j) {
            const float* wrow = (!SPLIT || j < J / 2)
                ? &W[(size_t)(o_lane + 16 * j) * KDIM]
                : &Wres[(size_t)(o_lane + 16 * (j - J / 2)) * KDIM];
            float4 wv = *(const float4*)&wrow[k4];
            #pragma unroll
            for (int i = 0; i < 4; ++i) {
                acc[i][j] += xv[i].x * wv.x + xv[i].y * wv.y
                           + xv[i].z * wv.z + xv[i].w * wv.w;
            }
        }
    }

    #pragma unroll
    for (int i = 0; i < 4; ++i) {
        int nn = node0 + ng + i;
        if (nn < n) {
            #pragma unroll
            for (int j = 0; j < J; ++j) {
                int o = o_lane + 16 * j;
                if (!SPLIT || j < J / 2)
                    y[(size_t)nn * 64 + o] = acc[i][j];
                else
                    yres[(size_t)nn * 64 + (o - 64)] = acc[i][j];
            }
        }
    }
}

// ---------------- CSR build ----------------
__global__ __launch_bounds__(256)
void hist_kernel(const int* __restrict__ dst, int* __restrict__ cnt, int E)
{
    int e = blockIdx.x * 256 + threadIdx.x;
    if (e < E) atomicAdd(&cnt[dst[e]], 1);
}

__global__ __launch_bounds__(256)
void scanA_kernel(const int* __restrict__ cnt, int* __restrict__ excl,
                  int* __restrict__ bsum, int n)
{
    __shared__ int sh[256];
    int i = blockIdx.x * 256 + threadIdx.x;
    int v = (i < n) ? cnt[i] : 0;
    sh[threadIdx.x] = v;
    __syncthreads();
    #pragma unroll
    for (int off = 1; off < 256; off <<= 1) {
        int t = (threadIdx.x >= off) ? sh[threadIdx.x - off] : 0;
        __syncthreads();
        sh[threadIdx.x] += t;
        __syncthreads();
    }
    if (i < n) excl[i] = sh[threadIdx.x] - v;
    if (threadIdx.x == 255) bsum[blockIdx.x] = sh[255];
}

__global__ __launch_bounds__(256)
void scanB_kernel(const int* __restrict__ bsum, int* __restrict__ bofs, int nb)
{
    __shared__ int sh[256];
    int v = (threadIdx.x < nb) ? bsum[threadIdx.x] : 0;
    sh[threadIdx.x] = v;
    __syncthreads();
    #pragma unroll
    for (int off = 1; off < 256; off <<= 1) {
        int t = (threadIdx.x >= off) ? sh[threadIdx.x - off] : 0;
        __syncthreads();
        sh[threadIdx.x] += t;
        __syncthreads();
    }
    if (threadIdx.x < nb) bofs[threadIdx.x] = sh[threadIdx.x] - v;
}

__global__ __launch_bounds__(256)
void scanC_kernel(const int* __restrict__ excl, const int* __restrict__ bofs,
                  int* __restrict__ rowptr, int* __restrict__ cur, int n, int E)
{
    int i = blockIdx.x * 256 + threadIdx.x;
    if (i < n) {
        int v = excl[i] + bofs[i >> 8];
        rowptr[i] = v;
        cur[i] = v;
    }
    if (i == n) rowptr[n] = E;
}

__global__ __launch_bounds__(256)
void scatter_kernel(const int* __restrict__ src, const int* __restrict__ dst,
                    int* __restrict__ cur, int* __restrict__ col, int E)
{
    int e = blockIdx.x * 256 + threadIdx.x;
    if (e < E) {
        int p = atomicAdd(&cur[dst[e]], 1);
        col[p] = src[e];
    }
}

// ---------------- hop: wave per node, lane = feature ----------------
__global__ __launch_bounds__(256)
void hop_csr_kernel(const float* __restrict__ fin, float* __restrict__ fout,
                    const int* __restrict__ rowptr, const int* __restrict__ col, int n)
{
    int node = blockIdx.x * 4 + (threadIdx.x >> 6);
    if (node >= n) return;
    int lane = threadIdx.x & 63;
    int beg = rowptr[node], end = rowptr[node + 1];
    float a0 = 0.f, a1 = 0.f, a2 = 0.f, a3 = 0.f;
    int i = beg;
    for (; i + 4 <= end; i += 4) {
        int s0 = col[i], s1 = col[i + 1], s2 = col[i + 2], s3 = col[i + 3];
        a0 += fin[(size_t)s0 * 64 + lane];
        a1 += fin[(size_t)s1 * 64 + lane];
        a2 += fin[(size_t)s2 * 64 + lane];
        a3 += fin[(size_t)s3 * 64 + lane];
    }
    for (; i < end; ++i) a0 += fin[(size_t)col[i] * 64 + lane];
    fout[(size_t)node * 64 + lane] = (a0 + a1) + (a2 + a3);
}

// ---------------- 3rd hop fused with attention combine ----------------
// MODE 0: layer 1 (res from res buffer, apply ELU)
// MODE 1: layer 2 (res = h0, no ELU)
template<int MODE>
__global__ __launch_bounds__(256)
void hop3_combine_kernel(const float* __restrict__ h0, const float* __restrict__ f1,
                         const float* __restrict__ f2,
                         const float* __restrict__ res, const float* __restrict__ att,
                         const float* __restrict__ bias, float* __restrict__ out,
                         const int* __restrict__ rowptr, const int* __restrict__ col, int n)
{
    int node = blockIdx.x * 4 + (threadIdx.x >> 6);
    if (node >= n) return;
    int lane = threadIdx.x & 63;
    size_t base = (size_t)node * 64 + lane;

    // f3 = gather-sum of f2 rows
    int beg = rowptr[node], end = rowptr[node + 1];
    float a0 = 0.f, a1 = 0.f, a2 = 0.f, a3 = 0.f;
    int i = beg;
    for (; i + 4 <= end; i += 4) {
        int s0 = col[i], s1 = col[i + 1], s2 = col[i + 2], s3 = col[i + 3];
        a0 += f2[(size_t)s0 * 64 + lane];
        a1 += f2[(size_t)s1 * 64 + lane];
        a2 += f2[(size_t)s2 * 64 + lane];
        a3 += f2[(size_t)s3 * 64 + lane];
    }
    for (; i < end; ++i) a0 += f2[(size_t)col[i] * 64 + lane];
    float v3 = (a0 + a1) + (a2 + a3);

    float v0 = h0[base], v1 = f1[base], v2 = f2[base];
    float alo = att[lane], ahi = att[64 + lane];

    float p0 = v0 * alo;                    // shared h0 . att_lo term
    float q0 = v0 * ahi;
    float q1 = v1 * ahi;
    float q2 = v2 * ahi;
    float q3 = v3 * ahi;
    #pragma unroll
    for (int off = 32; off > 0; off >>= 1) {
        p0 += __shfl_xor(p0, off);
        q0 += __shfl_xor(q0, off);
        q1 += __shfl_xor(q1, off);
        q2 += __shfl_xor(q2, off);
        q3 += __shfl_xor(q3, off);
    }
    float s0 = p0 + q0, s1 = p0 + q1, s2 = p0 + q2, s3 = p0 + q3;
    s0 = s0 > 0.f ? s0 : 0.2f * s0;
    s1 = s1 > 0.f ? s1 : 0.2f * s1;
    s2 = s2 > 0.f ? s2 : 0.2f * s2;
    s3 = s3 > 0.f ? s3 : 0.2f * s3;
    float m = fmaxf(fmaxf(s0, s1), fmaxf(s2, s3));
    float e0 = expf(s0 - m), e1 = expf(s1 - m), e2 = expf(s2 - m), e3 = expf(s3 - m);
    float inv = 1.f / (e0 + e1 + e2 + e3);
    float o = (e0 * v0 + e1 * v1 + e2 * v2 + e3 * v3) * inv;

    float r = (MODE == 0) ? res[base] : v0;
    o += r + bias[lane];
    if (MODE == 0) o = o > 0.f ? o : expm1f(o);   // ELU(alpha=1)
    out[base] = o;
}

extern "C" void kernel_launch(void* const* d_in, const int* in_sizes, int n_in,
                              void* d_out, int out_size, void* d_ws, size_t ws_size,
                              hipStream_t stream)
{
    const float* x     = (const float*)d_in[0];
    const int*   ei    = (const int*)  d_in[1];
    const float* W1    = (const float*)d_in[2];
    const float* att1  = (const float*)d_in[3];
    const float* bias1 = (const float*)d_in[4];
    const float* resW1 = (const float*)d_in[5];
    const float* W2    = (const float*)d_in[6];
    const float* att2  = (const float*)d_in[7];
    const float* bias2 = (const float*)d_in[8];

    const int N_ = in_sizes[0] / 128;
    const int E_ = in_sizes[1] / 2;
    const int* src = ei;
    const int* dst = ei + E_;

    float* out = (float*)d_out;
    size_t S = (size_t)N_ * 64;
    float* h0 = (float*)d_ws;
    float* f1 = h0 + S;
    float* f2 = f1 + S;
    int* rowptr = (int*)(f2 + S);        // N+1
    int* cur    = rowptr + (N_ + 1);     // N  (also the histogram cnt)
    int* excl   = cur + N_;              // N
    int* bsum   = excl + N_;             // 256
    int* bofs   = bsum + 256;            // 256
    int* col    = bofs + 256;            // E

    dim3 blk(256);
    int gemm_grid = (N_ + 63) / 64;
    int node_grid = (N_ + 3) / 4;
    int edge_grid = (E_ + 255) / 256;
    int nb        = (N_ + 255) / 256;    // scan blocks (<=256 required)

    // ---------------- CSR build (by dst) ----------------
    hipMemsetAsync(cur, 0, (size_t)N_ * sizeof(int), stream);
    hist_kernel<<<edge_grid, blk, 0, stream>>>(dst, cur, E_);
    scanA_kernel<<<nb, blk, 0, stream>>>(cur, excl, bsum, N_);
    scanB_kernel<<<1, blk, 0, stream>>>(bsum, bofs, nb);
    scanC_kernel<<<nb + 1, blk, 0, stream>>>(excl, bofs, rowptr, cur, N_, E_);
    scatter_kernel<<<edge_grid, blk, 0, stream>>>(src, dst, cur, col, E_);

    // ---------------- layer 1 ----------------
    gemm_kernel<128, 8, true><<<gemm_grid, blk, 0, stream>>>(x, W1, resW1, h0, out, N_);
    hop_csr_kernel<<<node_grid, blk, 0, stream>>>(h0, f1, rowptr, col, N_);
    hop_csr_kernel<<<node_grid, blk, 0, stream>>>(f1, f2, rowptr, col, N_);
    hop3_combine_kernel<0><<<node_grid, blk, 0, stream>>>(h0, f1, f2, out, att1, bias1, out,
                                                          rowptr, col, N_);

    // ---------------- layer 2 ----------------
    gemm_kernel<64, 4, false><<<gemm_grid, blk, 0, stream>>>(out, W2, nullptr, h0, nullptr, N_);
    hop_csr_kernel<<<node_grid, blk, 0, stream>>>(h0, f1, rowptr, col, N_);
    hop_csr_kernel<<<node_grid, blk, 0, stream>>>(f1, f2, rowptr, col, N_);
    hop3_combine_kernel<1><<<node_grid, blk, 0, stream>>>(h0, f1, f2, nullptr, att2, bias2, out,
                                                          rowptr, col, N_);
}

// Round 4
// 359.116 us; speedup vs baseline: 3.4891x; 1.3516x over previous
//
#include <hip/hip_runtime.h>
#include <math.h>

// ---------------------------------------------------------------------------
// AGDN via CSR-gather (no float atomics).
// GEMM: x-tile AND W both in LDS (64 nodes x 64 outputs per block; layer-1
//   splits W1/resW1 over blockIdx.y) -> VALU-bound inner loop of ds_read_b128
//   + FMA.  Hop gather: float4-per-lane, 4 edges per load instruction,
//   unroll 2 (8 edges in flight), shfl_xor(16,32) cross-slot reduce.
// ---------------------------------------------------------------------------

template<int KDIM>
__global__ __launch_bounds__(256)
void gemm64_kernel(const float* __restrict__ x,
                   const float* __restrict__ Wa, const float* __restrict__ Wb,
                   float* __restrict__ ya, float* __restrict__ yb, int n)
{
    constexpr int PAD = KDIM + 4;     // float4-aligned, 2-way-max LDS banking
    __shared__ float xs[64 * PAD];
    __shared__ float ws[64 * PAD];

    const float* W = (blockIdx.y == 0) ? Wa : Wb;
    float*       y = (blockIdx.y == 0) ? ya : yb;

    const int tid = threadIdx.x;
    const int node0 = blockIdx.x * 64;
    constexpr int K4 = KDIM / 4;

    for (int i = tid; i < 64 * K4; i += 256) {
        int r = i / K4, c4 = (i % K4) * 4;
        *(float4*)&ws[r * PAD + c4] = *(const float4*)&W[(size_t)r * KDIM + c4];
        int nn = node0 + r;
        float4 v = (nn < n) ? *(const float4*)&x[(size_t)nn * KDIM + c4]
                            : make_float4(0.f, 0.f, 0.f, 0.f);
        *(float4*)&xs[r * PAD + c4] = v;
    }
    __syncthreads();

    const int o_lane = tid & 15;       // outputs o = o_lane + 16j
    const int ng = tid >> 4;           // nodes ng*4 .. ng*4+3

    float acc[4][4] = {};
    #pragma unroll 2
    for (int k4 = 0; k4 < KDIM; k4 += 4) {
        float4 xv[4], wv[4];
        #pragma unroll
        for (int i = 0; i < 4; ++i)
            xv[i] = *(const float4*)&xs[(ng * 4 + i) * PAD + k4];
        #pragma unroll
        for (int j = 0; j < 4; ++j)
            wv[j] = *(const float4*)&ws[(o_lane + 16 * j) * PAD + k4];
        #pragma unroll
        for (int i = 0; i < 4; ++i)
            #pragma unroll
            for (int j = 0; j < 4; ++j)
                acc[i][j] += xv[i].x * wv[j].x + xv[i].y * wv[j].y
                           + xv[i].z * wv[j].z + xv[i].w * wv[j].w;
    }

    #pragma unroll
    for (int i = 0; i < 4; ++i) {
        int nn = node0 + ng * 4 + i;
        if (nn < n) {
            #pragma unroll
            for (int j = 0; j < 4; ++j)
                y[(size_t)nn * 64 + o_lane + 16 * j] = acc[i][j];
        }
    }
}

// ---------------- CSR build ----------------
__global__ __launch_bounds__(256)
void hist_kernel(const int* __restrict__ dst, int* __restrict__ cnt, int E)
{
    int e = blockIdx.x * 256 + threadIdx.x;
    if (e < E) atomicAdd(&cnt[dst[e]], 1);
}

__global__ __launch_bounds__(256)
void scanA_kernel(const int* __restrict__ cnt, int* __restrict__ excl,
                  int* __restrict__ bsum, int n)
{
    __shared__ int sh[256];
    int i = blockIdx.x * 256 + threadIdx.x;
    int v = (i < n) ? cnt[i] : 0;
    sh[threadIdx.x] = v;
    __syncthreads();
    #pragma unroll
    for (int off = 1; off < 256; off <<= 1) {
        int t = (threadIdx.x >= off) ? sh[threadIdx.x - off] : 0;
        __syncthreads();
        sh[threadIdx.x] += t;
        __syncthreads();
    }
    if (i < n) excl[i] = sh[threadIdx.x] - v;
    if (threadIdx.x == 255) bsum[blockIdx.x] = sh[255];
}

__global__ __launch_bounds__(256)
void scanB_kernel(const int* __restrict__ bsum, int* __restrict__ bofs, int nb)
{
    __shared__ int sh[256];
    int v = (threadIdx.x < nb) ? bsum[threadIdx.x] : 0;
    sh[threadIdx.x] = v;
    __syncthreads();
    #pragma unroll
    for (int off = 1; off < 256; off <<= 1) {
        int t = (threadIdx.x >= off) ? sh[threadIdx.x - off] : 0;
        __syncthreads();
        sh[threadIdx.x] += t;
        __syncthreads();
    }
    if (threadIdx.x < nb) bofs[threadIdx.x] = sh[threadIdx.x] - v;
}

__global__ __launch_bounds__(256)
void scanC_kernel(const int* __restrict__ excl, const int* __restrict__ bofs,
                  int* __restrict__ rowptr, int* __restrict__ cur, int n, int E)
{
    int i = blockIdx.x * 256 + threadIdx.x;
    if (i < n) {
        int v = excl[i] + bofs[i >> 8];
        rowptr[i] = v;
        cur[i] = v;
    }
    if (i == n) rowptr[n] = E;
}

__global__ __launch_bounds__(256)
void scatter_kernel(const int* __restrict__ src, const int* __restrict__ dst,
                    int* __restrict__ cur, int* __restrict__ col, int E)
{
    int e = blockIdx.x * 256 + threadIdx.x;
    if (e < E) {
        int p = atomicAdd(&cur[dst[e]], 1);
        col[p] = src[e];
    }
}

// ---------------- hop: wave per node; lane = (edge-slot, feature-quarter) ---
// One dwordx4 per iteration gathers 4 edges' 256B rows (1KB/instr).
__global__ __launch_bounds__(256)
void hop_csr_kernel(const float* __restrict__ fin, float* __restrict__ fout,
                    const int* __restrict__ rowptr, const int* __restrict__ col, int n)
{
    int node = blockIdx.x * 4 + (threadIdx.x >> 6);
    if (node >= n) return;
    int lane = threadIdx.x & 63;
    int sub = lane >> 4;            // edge slot 0..3
    int fq4 = (lane & 15) * 4;      // feature quarter start

    int beg = rowptr[node], end = rowptr[node + 1];
    int deg = end - beg;
    float4 acc = make_float4(0.f, 0.f, 0.f, 0.f);
    for (int b = 0; b < deg; b += 8) {
        int e0 = beg + b + sub, e1 = e0 + 4;
        float4 v0 = make_float4(0.f, 0.f, 0.f, 0.f);
        float4 v1 = make_float4(0.f, 0.f, 0.f, 0.f);
        if (e0 < end) { int s = col[e0]; v0 = *(const float4*)&fin[(size_t)s * 64 + fq4]; }
        if (e1 < end) { int s = col[e1]; v1 = *(const float4*)&fin[(size_t)s * 64 + fq4]; }
        acc.x += v0.x + v1.x; acc.y += v0.y + v1.y;
        acc.z += v0.z + v1.z; acc.w += v0.w + v1.w;
    }
    #pragma unroll
    for (int off = 16; off <= 32; off <<= 1) {
        acc.x += __shfl_xor(acc.x, off);
        acc.y += __shfl_xor(acc.y, off);
        acc.z += __shfl_xor(acc.z, off);
        acc.w += __shfl_xor(acc.w, off);
    }
    if (sub == 0) *(float4*)&fout[(size_t)node * 64 + fq4] = acc;
}

// ---------------- 3rd hop fused with attention combine ----------------
// MODE 0: layer 1 (res from res buffer, apply ELU)
// MODE 1: layer 2 (res = h0, no ELU)
template<int MODE>
__global__ __launch_bounds__(256)
void hop3_combine_kernel(const float* __restrict__ h0, const float* __restrict__ f1,
                         const float* __restrict__ f2,
                         const float* __restrict__ res, const float* __restrict__ att,
                         const float* __restrict__ bias, float* __restrict__ out,
                         const int* __restrict__ rowptr, const int* __restrict__ col, int n)
{
    int node = blockIdx.x * 4 + (threadIdx.x >> 6);
    if (node >= n) return;
    int lane = threadIdx.x & 63;
    int sub = lane >> 4;
    int fq4 = (lane & 15) * 4;
    size_t base = (size_t)node * 64 + lane;

    // f3 = gather-sum of f2 rows (float4-per-lane, 4 edges per instr)
    int beg = rowptr[node], end = rowptr[node + 1];
    int deg = end - beg;
    float4 acc = make_float4(0.f, 0.f, 0.f, 0.f);
    for (int b = 0; b < deg; b += 8) {
        int e0 = beg + b + sub, e1 = e0 + 4;
        float4 v0 = make_float4(0.f, 0.f, 0.f, 0.f);
        float4 v1 = make_float4(0.f, 0.f, 0.f, 0.f);
        if (e0 < end) { int s = col[e0]; v0 = *(const float4*)&f2[(size_t)s * 64 + fq4]; }
        if (e1 < end) { int s = col[e1]; v1 = *(const float4*)&f2[(size_t)s * 64 + fq4]; }
        acc.x += v0.x + v1.x; acc.y += v0.y + v1.y;
        acc.z += v0.z + v1.z; acc.w += v0.w + v1.w;
    }
    #pragma unroll
    for (int off = 16; off <= 32; off <<= 1) {
        acc.x += __shfl_xor(acc.x, off);
        acc.y += __shfl_xor(acc.y, off);
        acc.z += __shfl_xor(acc.z, off);
        acc.w += __shfl_xor(acc.w, off);
    }
    // redistribute: lane wants feature `lane` = component (lane&3) of quarter (lane>>2)
    int srcl = lane >> 2;
    float c0 = __shfl(acc.x, srcl), c1 = __shfl(acc.y, srcl);
    float c2 = __shfl(acc.z, srcl), c3 = __shfl(acc.w, srcl);
    int rsel = lane & 3;
    float v3 = (rsel == 0) ? c0 : (rsel == 1) ? c1 : (rsel == 2) ? c2 : c3;

    float v0 = h0[base], v1 = f1[base], v2 = f2[base];
    float alo = att[lane], ahi = att[64 + lane];

    float p0 = v0 * alo;                    // shared h0 . att_lo term
    float q0 = v0 * ahi;
    float q1 = v1 * ahi;
    float q2 = v2 * ahi;
    float q3 = v3 * ahi;
    #pragma unroll
    for (int off = 32; off > 0; off >>= 1) {
        p0 += __shfl_xor(p0, off);
        q0 += __shfl_xor(q0, off);
        q1 += __shfl_xor(q1, off);
        q2 += __shfl_xor(q2, off);
        q3 += __shfl_xor(q3, off);
    }
    float s0 = p0 + q0, s1 = p0 + q1, s2 = p0 + q2, s3 = p0 + q3;
    s0 = s0 > 0.f ? s0 : 0.2f * s0;
    s1 = s1 > 0.f ? s1 : 0.2f * s1;
    s2 = s2 > 0.f ? s2 : 0.2f * s2;
    s3 = s3 > 0.f ? s3 : 0.2f * s3;
    float m = fmaxf(fmaxf(s0, s1), fmaxf(s2, s3));
    float e0 = expf(s0 - m), e1 = expf(s1 - m), e2 = expf(s2 - m), e3 = expf(s3 - m);
    float inv = 1.f / (e0 + e1 + e2 + e3);
    float o = (e0 * v0 + e1 * v1 + e2 * v2 + e3 * v3) * inv;

    float r = (MODE == 0) ? res[base] : v0;
    o += r + bias[lane];
    if (MODE == 0) o = o > 0.f ? o : expm1f(o);   // ELU(alpha=1)
    out[base] = o;
}

extern "C" void kernel_launch(void* const* d_in, const int* in_sizes, int n_in,
                              void* d_out, int out_size, void* d_ws, size_t ws_size,
                              hipStream_t stream)
{
    const float* x     = (const float*)d_in[0];
    const int*   ei    = (const int*)  d_in[1];
    const float* W1    = (const float*)d_in[2];
    const float* att1  = (const float*)d_in[3];
    const float* bias1 = (const float*)d_in[4];
    const float* resW1 = (const float*)d_in[5];
    const float* W2    = (const float*)d_in[6];
    const float* att2  = (const float*)d_in[7];
    const float* bias2 = (const float*)d_in[8];

    const int N_ = in_sizes[0] / 128;
    const int E_ = in_sizes[1] / 2;
    const int* src = ei;
    const int* dst = ei + E_;

    float* out = (float*)d_out;
    size_t S = (size_t)N_ * 64;
    float* h0 = (float*)d_ws;
    float* f1 = h0 + S;
    float* f2 = f1 + S;
    int* rowptr = (int*)(f2 + S);        // N+1
    int* cur    = rowptr + (N_ + 1);     // N  (also the histogram cnt)
    int* excl   = cur + N_;              // N
    int* bsum   = excl + N_;             // 256
    int* bofs   = bsum + 256;            // 256
    int* col    = bofs + 256;            // E

    dim3 blk(256);
    int grid_n    = (N_ + 63) / 64;
    int node_grid = (N_ + 3) / 4;
    int edge_grid = (E_ + 255) / 256;
    int nb        = (N_ + 255) / 256;    // scan blocks (<=256 required)

    // ---------------- CSR build (by dst) ----------------
    hipMemsetAsync(cur, 0, (size_t)N_ * sizeof(int), stream);
    hist_kernel<<<edge_grid, blk, 0, stream>>>(dst, cur, E_);
    scanA_kernel<<<nb, blk, 0, stream>>>(cur, excl, bsum, N_);
    scanB_kernel<<<1, blk, 0, stream>>>(bsum, bofs, nb);
    scanC_kernel<<<nb + 1, blk, 0, stream>>>(excl, bofs, rowptr, cur, N_, E_);
    scatter_kernel<<<edge_grid, blk, 0, stream>>>(src, dst, cur, col, E_);

    // ---------------- layer 1 ----------------
    // blockIdx.y==0: h0 = x@W1^T ; blockIdx.y==1: res (in d_out) = x@resW1^T
    gemm64_kernel<128><<<dim3(grid_n, 2), blk, 0, stream>>>(x, W1, resW1, h0, out, N_);
    hop_csr_kernel<<<node_grid, blk, 0, stream>>>(h0, f1, rowptr, col, N_);
    hop_csr_kernel<<<node_grid, blk, 0, stream>>>(f1, f2, rowptr, col, N_);
    hop3_combine_kernel<0><<<node_grid, blk, 0, stream>>>(h0, f1, f2, out, att1, bias1, out,
                                                          rowptr, col, N_);

    // ---------------- layer 2 ----------------
    gemm64_kernel<64><<<dim3(grid_n, 1), blk, 0, stream>>>(out, W2, W2, h0, h0, N_);
    hop_csr_kernel<<<node_grid, blk, 0, stream>>>(h0, f1, rowptr, col, N_);
    hop_csr_kernel<<<node_grid, blk, 0, stream>>>(f1, f2, rowptr, col, N_);
    hop3_combine_kernel<1><<<node_grid, blk, 0, stream>>>(h0, f1, f2, nullptr, att2, bias2, out,
                                                          rowptr, col, N_);
}

// Round 5
// 287.622 us; speedup vs baseline: 4.3564x; 1.2486x over previous
//
#include <hip/hip_runtime.h>
#include <math.h>

// ---------------------------------------------------------------------------
// AGDN via CSR-gather. CSR built per call with a two-level LDS counting sort
// (no global atomics, coalesced writes):
//   K1 coarse hist (dst>>8) -> table[bin][block]
//   scanA/B     -> per-(bin,block) bases
//   K3 per-block LDS reorder -> packed[] = (dst<<16|src), coalesced runs
//   K4 per-bucket fine hist -> cnt[dst]
//   scanA/B/C   -> rowptr
//   K5 per-bucket LDS scatter -> col segment built in LDS, coalesced copy-out
// GEMM: x/W in LDS, K-chunked (KC=64) -> 34.8KB LDS, 4 blocks/CU.
// Hops: wave-per-node float4 gather, 4 edges per load instr, unroll 2.
// ---------------------------------------------------------------------------

#define EPB 4096     // edges per partition block
#define CAP 8192     // LDS col capacity per bucket (avg ~4096)

template<int KDIM, int KC>
__global__ __launch_bounds__(256)
void gemm64_kernel(const float* __restrict__ x,
                   const float* __restrict__ Wa, const float* __restrict__ Wb,
                   float* __restrict__ ya, float* __restrict__ yb, int n)
{
    constexpr int PAD = KC + 4;
    __shared__ float xs[64 * PAD];
    __shared__ float ws[64 * PAD];

    const float* W = (blockIdx.y == 0) ? Wa : Wb;
    float*       y = (blockIdx.y == 0) ? ya : yb;

    const int tid = threadIdx.x;
    const int node0 = blockIdx.x * 64;
    const int o_lane = tid & 15;       // outputs o = o_lane + 16j
    const int ng = tid >> 4;           // nodes ng*4 .. ng*4+3
    constexpr int K4C = KC / 4;

    float acc[4][4] = {};
    for (int kc = 0; kc < KDIM; kc += KC) {
        for (int i = tid; i < 64 * K4C; i += 256) {
            int r = i / K4C, c4 = (i % K4C) * 4;
            *(float4*)&ws[r * PAD + c4] =
                *(const float4*)&W[(size_t)r * KDIM + kc + c4];
            int nn = node0 + r;
            float4 v = (nn < n) ? *(const float4*)&x[(size_t)nn * KDIM + kc + c4]
                                : make_float4(0.f, 0.f, 0.f, 0.f);
            *(float4*)&xs[r * PAD + c4] = v;
        }
        __syncthreads();
        #pragma unroll 2
        for (int k4 = 0; k4 < KC; k4 += 4) {
            float4 xv[4], wv[4];
            #pragma unroll
            for (int i = 0; i < 4; ++i)
                xv[i] = *(const float4*)&xs[(ng * 4 + i) * PAD + k4];
            #pragma unroll
            for (int j = 0; j < 4; ++j)
                wv[j] = *(const float4*)&ws[(o_lane + 16 * j) * PAD + k4];
            #pragma unroll
            for (int i = 0; i < 4; ++i)
                #pragma unroll
                for (int j = 0; j < 4; ++j)
                    acc[i][j] += xv[i].x * wv[j].x + xv[i].y * wv[j].y
                               + xv[i].z * wv[j].z + xv[i].w * wv[j].w;
        }
        __syncthreads();
    }

    #pragma unroll
    for (int i = 0; i < 4; ++i) {
        int nn = node0 + ng * 4 + i;
        if (nn < n) {
            #pragma unroll
            for (int j = 0; j < 4; ++j)
                y[(size_t)nn * 64 + o_lane + 16 * j] = acc[i][j];
        }
    }
}

// ---------------- CSR build: two-level LDS counting sort ----------------
__global__ __launch_bounds__(256)
void part_hist_kernel(const int* __restrict__ dst, int* __restrict__ table,
                      int E, int NB)
{
    __shared__ int h[256];
    h[threadIdx.x] = 0;
    __syncthreads();
    int base = blockIdx.x * EPB;
    for (int i = threadIdx.x; i < EPB; i += 256) {
        int e = base + i;
        if (e < E) atomicAdd(&h[((unsigned)dst[e]) >> 8], 1);
    }
    __syncthreads();
    table[threadIdx.x * NB + blockIdx.x] = h[threadIdx.x];   // bin-major
}

__global__ __launch_bounds__(256)
void scanA_kernel(const int* __restrict__ cnt, int* __restrict__ excl,
                  int* __restrict__ bsum, int n)
{
    __shared__ int sh[256];
    int i = blockIdx.x * 256 + threadIdx.x;
    int v = (i < n) ? cnt[i] : 0;
    sh[threadIdx.x] = v;
    __syncthreads();
    #pragma unroll
    for (int off = 1; off < 256; off <<= 1) {
        int t = (threadIdx.x >= off) ? sh[threadIdx.x - off] : 0;
        __syncthreads();
        sh[threadIdx.x] += t;
        __syncthreads();
    }
    if (i < n) excl[i] = sh[threadIdx.x] - v;
    if (threadIdx.x == 255) bsum[blockIdx.x] = sh[255];
}

__global__ __launch_bounds__(256)
void scanB_kernel(const int* __restrict__ bsum, int* __restrict__ bofs, int nb)
{
    __shared__ int sh[256];
    int v = (threadIdx.x < nb) ? bsum[threadIdx.x] : 0;
    sh[threadIdx.x] = v;
    __syncthreads();
    #pragma unroll
    for (int off = 1; off < 256; off <<= 1) {
        int t = (threadIdx.x >= off) ? sh[threadIdx.x - off] : 0;
        __syncthreads();
        sh[threadIdx.x] += t;
        __syncthreads();
    }
    if (threadIdx.x < nb) bofs[threadIdx.x] = sh[threadIdx.x] - v;
}

__global__ __launch_bounds__(256)
void scanC_kernel(const int* __restrict__ excl, const int* __restrict__ bofs,
                  int* __restrict__ rowptr, int n, int E)
{
    int i = blockIdx.x * 256 + threadIdx.x;
    if (i < n) rowptr[i] = excl[i] + bofs[i >> 8];
    if (i == n) rowptr[n] = E;
}

// per-block LDS reorder -> packed (dst<<16 | src), coalesced run writes
__global__ __launch_bounds__(256)
void part_scatter_kernel(const int* __restrict__ src, const int* __restrict__ dst,
                         const int* __restrict__ exclT, const int* __restrict__ bofsT,
                         unsigned int* __restrict__ packed, int E, int NB)
{
    __shared__ int lhist[256];
    __shared__ int sh[256];
    __shared__ int lexcl[256];
    __shared__ int lcur[256];
    __shared__ int gb2[256];
    __shared__ unsigned int lp[EPB];
    __shared__ unsigned char lbin[EPB];

    const int tid = threadIdx.x;
    const int base = blockIdx.x * EPB;
    const int cntE = min(EPB, E - base);

    unsigned int pv[16];
    int pb[16];
    lhist[tid] = 0;
    __syncthreads();
    #pragma unroll
    for (int it = 0; it < 16; ++it) {
        int i = it * 256 + tid;
        pv[it] = 0; pb[it] = -1;
        if (i < cntE) {
            int e = base + i;
            unsigned int p = (((unsigned)dst[e]) << 16) | (unsigned)src[e];
            pv[it] = p;
            pb[it] = (int)(p >> 24);
            atomicAdd(&lhist[pb[it]], 1);
        }
    }
    __syncthreads();
    // exclusive scan of lhist
    sh[tid] = lhist[tid];
    __syncthreads();
    #pragma unroll
    for (int off = 1; off < 256; off <<= 1) {
        int t = (tid >= off) ? sh[tid - off] : 0;
        __syncthreads();
        sh[tid] += t;
        __syncthreads();
    }
    lexcl[tid] = sh[tid] - lhist[tid];
    lcur[tid] = sh[tid] - lhist[tid];
    int ti = tid * NB + blockIdx.x;
    gb2[tid] = exclT[ti] + bofsT[ti >> 8] - lexcl[tid];
    __syncthreads();
    #pragma unroll
    for (int it = 0; it < 16; ++it) {
        if (pb[it] >= 0) {
            int slot = atomicAdd(&lcur[pb[it]], 1);
            lp[slot] = pv[it];
            lbin[slot] = (unsigned char)pb[it];
        }
    }
    __syncthreads();
    for (int i = tid; i < cntE; i += 256)
        packed[gb2[lbin[i]] + i] = lp[i];
}

__global__ __launch_bounds__(256)
void bucket_hist_kernel(const unsigned int* __restrict__ packed,
                        const int* __restrict__ exclT, const int* __restrict__ bofsT,
                        int* __restrict__ cnt, int E, int NB, int N)
{
    __shared__ int h[256];
    const int b = blockIdx.x;
    h[threadIdx.x] = 0;
    __syncthreads();
    int i0 = exclT[b * NB] + bofsT[(b * NB) >> 8];
    int bn = (b + 1) * NB;
    int i1 = exclT[bn] + bofsT[bn >> 8];
    for (int i = i0 + threadIdx.x; i < i1; i += 256)
        atomicAdd(&h[(packed[i] >> 16) & 255], 1);
    __syncthreads();
    int d = b * 256 + threadIdx.x;
    if (d < N) cnt[d] = h[threadIdx.x];
}

__global__ __launch_bounds__(256)
void bucket_scatter_kernel(const unsigned int* __restrict__ packed,
                           const int* __restrict__ exclT, const int* __restrict__ bofsT,
                           const int* __restrict__ rowptr, int* __restrict__ col,
                           int E, int NB, int N)
{
    __shared__ int curL[256];
    __shared__ int colL[CAP];
    const int b = blockIdx.x;
    const int t = threadIdx.x;
    int i0 = exclT[b * NB] + bofsT[(b * NB) >> 8];
    int bn = (b + 1) * NB;
    int i1 = exclT[bn] + bofsT[bn >> 8];
    int d0 = b * 256;
    int colbase = rowptr[d0];
    int dend = min(d0 + 256, N);
    int colend = rowptr[dend];
    int cB = colend - colbase;
    curL[t] = (d0 + t < N) ? (rowptr[d0 + t] - colbase) : 0;
    __syncthreads();
    for (int i = i0 + t; i < i1; i += 256) {
        unsigned int p = packed[i];
        int lo = (p >> 16) & 255;
        int s = (int)(p & 0xFFFFu);
        int r = atomicAdd(&curL[lo], 1);
        if (r < CAP) colL[r] = s;
        else col[colbase + r] = s;
    }
    __syncthreads();
    for (int i = t; i < cB && i < CAP; i += 256)
        col[colbase + i] = colL[i];
}

// ---------------- hop: wave per node; lane = (edge-slot, feature-quarter) ---
__global__ __launch_bounds__(256)
void hop_csr_kernel(const float* __restrict__ fin, float* __restrict__ fout,
                    const int* __restrict__ rowptr, const int* __restrict__ col, int n)
{
    int node = blockIdx.x * 4 + (threadIdx.x >> 6);
    if (node >= n) return;
    int lane = threadIdx.x & 63;
    int sub = lane >> 4;            // edge slot 0..3
    int fq4 = (lane & 15) * 4;      // feature quarter start

    int beg = rowptr[node], end = rowptr[node + 1];
    int deg = end - beg;
    float4 acc = make_float4(0.f, 0.f, 0.f, 0.f);
    for (int b = 0; b < deg; b += 8) {
        int e0 = beg + b + sub, e1 = e0 + 4;
        float4 v0 = make_float4(0.f, 0.f, 0.f, 0.f);
        float4 v1 = make_float4(0.f, 0.f, 0.f, 0.f);
        if (e0 < end) { int s = col[e0]; v0 = *(const float4*)&fin[(size_t)s * 64 + fq4]; }
        if (e1 < end) { int s = col[e1]; v1 = *(const float4*)&fin[(size_t)s * 64 + fq4]; }
        acc.x += v0.x + v1.x; acc.y += v0.y + v1.y;
        acc.z += v0.z + v1.z; acc.w += v0.w + v1.w;
    }
    #pragma unroll
    for (int off = 16; off <= 32; off <<= 1) {
        acc.x += __shfl_xor(acc.x, off);
        acc.y += __shfl_xor(acc.y, off);
        acc.z += __shfl_xor(acc.z, off);
        acc.w += __shfl_xor(acc.w, off);
    }
    if (sub == 0) *(float4*)&fout[(size_t)node * 64 + fq4] = acc;
}

// ---------------- 3rd hop fused with attention combine ----------------
template<int MODE>
__global__ __launch_bounds__(256)
void hop3_combine_kernel(const float* __restrict__ h0, const float* __restrict__ f1,
                         const float* __restrict__ f2,
                         const float* __restrict__ res, const float* __restrict__ att,
                         const float* __restrict__ bias, float* __restrict__ out,
                         const int* __restrict__ rowptr, const int* __restrict__ col, int n)
{
    int node = blockIdx.x * 4 + (threadIdx.x >> 6);
    if (node >= n) return;
    int lane = threadIdx.x & 63;
    int sub = lane >> 4;
    int fq4 = (lane & 15) * 4;
    size_t base = (size_t)node * 64 + lane;

    int beg = rowptr[node], end = rowptr[node + 1];
    int deg = end - beg;
    float4 acc = make_float4(0.f, 0.f, 0.f, 0.f);
    for (int b = 0; b < deg; b += 8) {
        int e0 = beg + b + sub, e1 = e0 + 4;
        float4 v0 = make_float4(0.f, 0.f, 0.f, 0.f);
        float4 v1 = make_float4(0.f, 0.f, 0.f, 0.f);
        if (e0 < end) { int s = col[e0]; v0 = *(const float4*)&f2[(size_t)s * 64 + fq4]; }
        if (e1 < end) { int s = col[e1]; v1 = *(const float4*)&f2[(size_t)s * 64 + fq4]; }
        acc.x += v0.x + v1.x; acc.y += v0.y + v1.y;
        acc.z += v0.z + v1.z; acc.w += v0.w + v1.w;
    }
    #pragma unroll
    for (int off = 16; off <= 32; off <<= 1) {
        acc.x += __shfl_xor(acc.x, off);
        acc.y += __shfl_xor(acc.y, off);
        acc.z += __shfl_xor(acc.z, off);
        acc.w += __shfl_xor(acc.w, off);
    }
    int srcl = lane >> 2;
    float c0 = __shfl(acc.x, srcl), c1 = __shfl(acc.y, srcl);
    float c2 = __shfl(acc.z, srcl), c3 = __shfl(acc.w, srcl);
    int rsel = lane & 3;
    float v3 = (rsel == 0) ? c0 : (rsel == 1) ? c1 : (rsel == 2) ? c2 : c3;

    float v0 = h0[base], v1 = f1[base], v2 = f2[base];
    float alo = att[lane], ahi = att[64 + lane];

    float p0 = v0 * alo;
    float q0 = v0 * ahi;
    float q1 = v1 * ahi;
    float q2 = v2 * ahi;
    float q3 = v3 * ahi;
    #pragma unroll
    for (int off = 32; off > 0; off >>= 1) {
        p0 += __shfl_xor(p0, off);
        q0 += __shfl_xor(q0, off);
        q1 += __shfl_xor(q1, off);
        q2 += __shfl_xor(q2, off);
        q3 += __shfl_xor(q3, off);
    }
    float s0 = p0 + q0, s1 = p0 + q1, s2 = p0 + q2, s3 = p0 + q3;
    s0 = s0 > 0.f ? s0 : 0.2f * s0;
    s1 = s1 > 0.f ? s1 : 0.2f * s1;
    s2 = s2 > 0.f ? s2 : 0.2f * s2;
    s3 = s3 > 0.f ? s3 : 0.2f * s3;
    float m = fmaxf(fmaxf(s0, s1), fmaxf(s2, s3));
    float e0 = expf(s0 - m), e1 = expf(s1 - m), e2 = expf(s2 - m), e3 = expf(s3 - m);
    float inv = 1.f / (e0 + e1 + e2 + e3);
    float o = (e0 * v0 + e1 * v1 + e2 * v2 + e3 * v3) * inv;

    float r = (MODE == 0) ? res[base] : v0;
    o += r + bias[lane];
    if (MODE == 0) o = o > 0.f ? o : expm1f(o);
    out[base] = o;
}

extern "C" void kernel_launch(void* const* d_in, const int* in_sizes, int n_in,
                              void* d_out, int out_size, void* d_ws, size_t ws_size,
                              hipStream_t stream)
{
    const float* x     = (const float*)d_in[0];
    const int*   ei    = (const int*)  d_in[1];
    const float* W1    = (const float*)d_in[2];
    const float* att1  = (const float*)d_in[3];
    const float* bias1 = (const float*)d_in[4];
    const float* resW1 = (const float*)d_in[5];
    const float* W2    = (const float*)d_in[6];
    const float* att2  = (const float*)d_in[7];
    const float* bias2 = (const float*)d_in[8];

    const int N_ = in_sizes[0] / 128;
    const int E_ = in_sizes[1] / 2;
    const int* src = ei;
    const int* dst = ei + E_;

    float* out = (float*)d_out;
    size_t S = (size_t)N_ * 64;
    float* h0 = (float*)d_ws;
    float* f1 = h0 + S;
    float* f2 = f1 + S;
    int* rowptr = (int*)(f2 + S);        // N+1
    int* cnt    = rowptr + (N_ + 1);     // N
    int* excl   = cnt + N_;              // N
    int* bsum   = excl + N_;             // 256
    int* bofs   = bsum + 256;            // 256
    int* col    = bofs + 256;            // E

    const int NB    = (E_ + EPB - 1) / EPB;      // 196 partition blocks (<=256)
    const int NBUCK = (N_ + 255) / 256;          // 196 dst buckets

    // aliases (consumed before f1/f2 are first written by the hops)
    unsigned int* packed = (unsigned int*)f1;    // E
    int* table = (int*)f2;                       // 256*NB
    int* exclT = table + 256 * NB;               // 256*NB
    int* bsumT = exclT + 256 * NB;               // 256
    int* bofsT = bsumT + 256;                    // 256

    dim3 blk(256);
    int grid_n    = (N_ + 63) / 64;
    int node_grid = (N_ + 3) / 4;
    int nb        = (N_ + 255) / 256;
    int nT        = 256 * NB;
    int nbT       = (nT + 255) / 256;            // == NB

    // ---------------- CSR build ----------------
    part_hist_kernel<<<NB, blk, 0, stream>>>(dst, table, E_, NB);
    scanA_kernel<<<nbT, blk, 0, stream>>>(table, exclT, bsumT, nT);
    scanB_kernel<<<1, blk, 0, stream>>>(bsumT, bofsT, nbT);
    part_scatter_kernel<<<NB, blk, 0, stream>>>(src, dst, exclT, bofsT, packed, E_, NB);
    bucket_hist_kernel<<<NBUCK, blk, 0, stream>>>(packed, exclT, bofsT, cnt, E_, NB, N_);
    scanA_kernel<<<nb, blk, 0, stream>>>(cnt, excl, bsum, N_);
    scanB_kernel<<<1, blk, 0, stream>>>(bsum, bofs, nb);
    scanC_kernel<<<nb + 1, blk, 0, stream>>>(excl, bofs, rowptr, N_, E_);
    bucket_scatter_kernel<<<NBUCK, blk, 0, stream>>>(packed, exclT, bofsT, rowptr, col,
                                                     E_, NB, N_);

    // ---------------- layer 1 ----------------
    gemm64_kernel<128, 64><<<dim3(grid_n, 2), blk, 0, stream>>>(x, W1, resW1, h0, out, N_);
    hop_csr_kernel<<<node_grid, blk, 0, stream>>>(h0, f1, rowptr, col, N_);
    hop_csr_kernel<<<node_grid, blk, 0, stream>>>(f1, f2, rowptr, col, N_);
    hop3_combine_kernel<0><<<node_grid, blk, 0, stream>>>(h0, f1, f2, out, att1, bias1, out,
                                                          rowptr, col, N_);

    // ---------------- layer 2 ----------------
    gemm64_kernel<64, 64><<<dim3(grid_n, 1), blk, 0, stream>>>(out, W2, W2, h0, h0, N_);
    hop_csr_kernel<<<node_grid, blk, 0, stream>>>(h0, f1, rowptr, col, N_);
    hop_csr_kernel<<<node_grid, blk, 0, stream>>>(f1, f2, rowptr, col, N_);
    hop3_combine_kernel<1><<<node_grid, blk, 0, stream>>>(h0, f1, f2, nullptr, att2, bias2, out,
                                                          rowptr, col, N_);
}

// Round 6
// 246.345 us; speedup vs baseline: 5.0864x; 1.1676x over previous
//
#include <hip/hip_runtime.h>
#include <math.h>

// ---------------------------------------------------------------------------
// AGDN via CSR-gather. Propagated features (h0,f1,f2) stored as bf16:
//   halves gather traffic, doubles L2 coverage. One uint4 load = 8 bf16 =
//   one edge row octet; 8 lanes/edge -> 8 edges per load instruction.
// CSR built per call with a two-level LDS counting sort (round-5 scheme).
// GEMM: x/W in LDS, K-chunked (KC=64), 4x4 register tile.
// ---------------------------------------------------------------------------

#define EPB 4096     // edges per partition block
#define CAP 8192     // LDS col capacity per bucket (avg ~4096)

__device__ __forceinline__ float bf2f(unsigned short u)
{
    unsigned int t = ((unsigned int)u) << 16;
    return __builtin_bit_cast(float, t);
}
__device__ __forceinline__ unsigned short f2bf(float f)
{
    unsigned int t = __builtin_bit_cast(unsigned int, f);
    t += 0x7FFFu + ((t >> 16) & 1u);          // round-to-nearest-even
    return (unsigned short)(t >> 16);
}

// unpack uint (2 bf16) -> 2 floats
__device__ __forceinline__ void up2(unsigned int u, float& lo, float& hi)
{
    lo = __builtin_bit_cast(float, u << 16);
    hi = __builtin_bit_cast(float, u & 0xFFFF0000u);
}

// ---------------- GEMM: y(bf16) for blockIdx.y==0, yres(fp32) for ==1 ------
template<int KDIM, int KC>
__global__ __launch_bounds__(256)
void gemm64_kernel(const float* __restrict__ x,
                   const float* __restrict__ Wa, const float* __restrict__ Wb,
                   unsigned short* __restrict__ ya, float* __restrict__ yb, int n)
{
    constexpr int PAD = KC + 4;
    __shared__ float xs[64 * PAD];
    __shared__ float ws[64 * PAD];

    const float* W = (blockIdx.y == 0) ? Wa : Wb;

    const int tid = threadIdx.x;
    const int node0 = blockIdx.x * 64;
    const int o_lane = tid & 15;       // outputs o = o_lane + 16j
    const int ng = tid >> 4;           // nodes ng*4 .. ng*4+3
    constexpr int K4C = KC / 4;

    float acc[4][4] = {};
    for (int kc = 0; kc < KDIM; kc += KC) {
        for (int i = tid; i < 64 * K4C; i += 256) {
            int r = i / K4C, c4 = (i % K4C) * 4;
            *(float4*)&ws[r * PAD + c4] =
                *(const float4*)&W[(size_t)r * KDIM + kc + c4];
            int nn = node0 + r;
            float4 v = (nn < n) ? *(const float4*)&x[(size_t)nn * KDIM + kc + c4]
                                : make_float4(0.f, 0.f, 0.f, 0.f);
            *(float4*)&xs[r * PAD + c4] = v;
        }
        __syncthreads();
        #pragma unroll 2
        for (int k4 = 0; k4 < KC; k4 += 4) {
            float4 xv[4], wv[4];
            #pragma unroll
            for (int i = 0; i < 4; ++i)
                xv[i] = *(const float4*)&xs[(ng * 4 + i) * PAD + k4];
            #pragma unroll
            for (int j = 0; j < 4; ++j)
                wv[j] = *(const float4*)&ws[(o_lane + 16 * j) * PAD + k4];
            #pragma unroll
            for (int i = 0; i < 4; ++i)
                #pragma unroll
                for (int j = 0; j < 4; ++j)
                    acc[i][j] += xv[i].x * wv[j].x + xv[i].y * wv[j].y
                               + xv[i].z * wv[j].z + xv[i].w * wv[j].w;
        }
        __syncthreads();
    }

    #pragma unroll
    for (int i = 0; i < 4; ++i) {
        int nn = node0 + ng * 4 + i;
        if (nn < n) {
            if (blockIdx.y == 0) {
                #pragma unroll
                for (int j = 0; j < 4; ++j)
                    ya[(size_t)nn * 64 + o_lane + 16 * j] = f2bf(acc[i][j]);
            } else {
                #pragma unroll
                for (int j = 0; j < 4; ++j)
                    yb[(size_t)nn * 64 + o_lane + 16 * j] = acc[i][j];
            }
        }
    }
}

// ---------------- CSR build: two-level LDS counting sort ----------------
__global__ __launch_bounds__(256)
void part_hist_kernel(const int* __restrict__ dst, int* __restrict__ table,
                      int E, int NB)
{
    __shared__ int h[256];
    h[threadIdx.x] = 0;
    __syncthreads();
    int base = blockIdx.x * EPB;
    for (int i = threadIdx.x; i < EPB; i += 256) {
        int e = base + i;
        if (e < E) atomicAdd(&h[((unsigned)dst[e]) >> 8], 1);
    }
    __syncthreads();
    table[threadIdx.x * NB + blockIdx.x] = h[threadIdx.x];   // bin-major
}

__global__ __launch_bounds__(256)
void scanA_kernel(const int* __restrict__ cnt, int* __restrict__ excl,
                  int* __restrict__ bsum, int n)
{
    __shared__ int sh[256];
    int i = blockIdx.x * 256 + threadIdx.x;
    int v = (i < n) ? cnt[i] : 0;
    sh[threadIdx.x] = v;
    __syncthreads();
    #pragma unroll
    for (int off = 1; off < 256; off <<= 1) {
        int t = (threadIdx.x >= off) ? sh[threadIdx.x - off] : 0;
        __syncthreads();
        sh[threadIdx.x] += t;
        __syncthreads();
    }
    if (i < n) excl[i] = sh[threadIdx.x] - v;
    if (threadIdx.x == 255) bsum[blockIdx.x] = sh[255];
}

__global__ __launch_bounds__(256)
void scanB_kernel(const int* __restrict__ bsum, int* __restrict__ bofs, int nb)
{
    __shared__ int sh[256];
    int v = (threadIdx.x < nb) ? bsum[threadIdx.x] : 0;
    sh[threadIdx.x] = v;
    __syncthreads();
    #pragma unroll
    for (int off = 1; off < 256; off <<= 1) {
        int t = (threadIdx.x >= off) ? sh[threadIdx.x - off] : 0;
        __syncthreads();
        sh[threadIdx.x] += t;
        __syncthreads();
    }
    if (threadIdx.x < nb) bofs[threadIdx.x] = sh[threadIdx.x] - v;
}

__global__ __launch_bounds__(256)
void scanC_kernel(const int* __restrict__ excl, const int* __restrict__ bofs,
                  int* __restrict__ rowptr, int n, int E)
{
    int i = blockIdx.x * 256 + threadIdx.x;
    if (i < n) rowptr[i] = excl[i] + bofs[i >> 8];
    if (i == n) rowptr[n] = E;
}

__global__ __launch_bounds__(256)
void part_scatter_kernel(const int* __restrict__ src, const int* __restrict__ dst,
                         const int* __restrict__ exclT, const int* __restrict__ bofsT,
                         unsigned int* __restrict__ packed, int E, int NB)
{
    __shared__ int lhist[256];
    __shared__ int sh[256];
    __shared__ int lexcl[256];
    __shared__ int lcur[256];
    __shared__ int gb2[256];
    __shared__ unsigned int lp[EPB];
    __shared__ unsigned char lbin[EPB];

    const int tid = threadIdx.x;
    const int base = blockIdx.x * EPB;
    const int cntE = min(EPB, E - base);

    unsigned int pv[16];
    int pb[16];
    lhist[tid] = 0;
    __syncthreads();
    #pragma unroll
    for (int it = 0; it < 16; ++it) {
        int i = it * 256 + tid;
        pv[it] = 0; pb[it] = -1;
        if (i < cntE) {
            int e = base + i;
            unsigned int p = (((unsigned)dst[e]) << 16) | (unsigned)src[e];
            pv[it] = p;
            pb[it] = (int)(p >> 24);
            atomicAdd(&lhist[pb[it]], 1);
        }
    }
    __syncthreads();
    sh[tid] = lhist[tid];
    __syncthreads();
    #pragma unroll
    for (int off = 1; off < 256; off <<= 1) {
        int t = (tid >= off) ? sh[tid - off] : 0;
        __syncthreads();
        sh[tid] += t;
        __syncthreads();
    }
    lexcl[tid] = sh[tid] - lhist[tid];
    lcur[tid] = sh[tid] - lhist[tid];
    int ti = tid * NB + blockIdx.x;
    gb2[tid] = exclT[ti] + bofsT[ti >> 8] - lexcl[tid];
    __syncthreads();
    #pragma unroll
    for (int it = 0; it < 16; ++it) {
        if (pb[it] >= 0) {
            int slot = atomicAdd(&lcur[pb[it]], 1);
            lp[slot] = pv[it];
            lbin[slot] = (unsigned char)pb[it];
        }
    }
    __syncthreads();
    for (int i = tid; i < cntE; i += 256)
        packed[gb2[lbin[i]] + i] = lp[i];
}

__global__ __launch_bounds__(256)
void bucket_hist_kernel(const unsigned int* __restrict__ packed,
                        const int* __restrict__ exclT, const int* __restrict__ bofsT,
                        int* __restrict__ cnt, int E, int NB, int N)
{
    __shared__ int h[256];
    const int b = blockIdx.x;
    h[threadIdx.x] = 0;
    __syncthreads();
    int i0 = exclT[b * NB] + bofsT[(b * NB) >> 8];
    int bn = (b + 1) * NB;
    int i1 = exclT[bn] + bofsT[bn >> 8];
    for (int i = i0 + threadIdx.x; i < i1; i += 256)
        atomicAdd(&h[(packed[i] >> 16) & 255], 1);
    __syncthreads();
    int d = b * 256 + threadIdx.x;
    if (d < N) cnt[d] = h[threadIdx.x];
}

__global__ __launch_bounds__(256)
void bucket_scatter_kernel(const unsigned int* __restrict__ packed,
                           const int* __restrict__ exclT, const int* __restrict__ bofsT,
                           const int* __restrict__ rowptr, int* __restrict__ col,
                           int E, int NB, int N)
{
    __shared__ int curL[256];
    __shared__ int colL[CAP];
    const int b = blockIdx.x;
    const int t = threadIdx.x;
    int i0 = exclT[b * NB] + bofsT[(b * NB) >> 8];
    int bn = (b + 1) * NB;
    int i1 = exclT[bn] + bofsT[bn >> 8];
    int d0 = b * 256;
    int colbase = rowptr[d0];
    int dend = min(d0 + 256, N);
    int colend = rowptr[dend];
    int cB = colend - colbase;
    curL[t] = (d0 + t < N) ? (rowptr[d0 + t] - colbase) : 0;
    __syncthreads();
    for (int i = i0 + t; i < i1; i += 256) {
        unsigned int p = packed[i];
        int lo = (p >> 16) & 255;
        int s = (int)(p & 0xFFFFu);
        int r = atomicAdd(&curL[lo], 1);
        if (r < CAP) colL[r] = s;
        else col[colbase + r] = s;
    }
    __syncthreads();
    for (int i = t; i < cB && i < CAP; i += 256)
        col[colbase + i] = colL[i];
}

// ---------------- hop: wave per node; 8 lanes/edge, 8 edges/instr ----------
__global__ __launch_bounds__(256)
void hop_csr_kernel(const unsigned short* __restrict__ fin,
                    unsigned short* __restrict__ fout,
                    const int* __restrict__ rowptr, const int* __restrict__ col, int n)
{
    int node = blockIdx.x * 4 + (threadIdx.x >> 6);
    if (node >= n) return;
    int lane = threadIdx.x & 63;
    int sub = lane >> 3;            // edge slot 0..7
    int fo = (lane & 7) * 8;        // feature octet start

    int beg = rowptr[node], end = rowptr[node + 1];
    int deg = end - beg;
    float a[8] = {};
    for (int b = 0; b < deg; b += 16) {
        int e0 = beg + b + sub, e1 = e0 + 8;
        uint4 u0 = make_uint4(0, 0, 0, 0), u1 = make_uint4(0, 0, 0, 0);
        if (e0 < end) { int s = col[e0]; u0 = *(const uint4*)&fin[(size_t)s * 64 + fo]; }
        if (e1 < end) { int s = col[e1]; u1 = *(const uint4*)&fin[(size_t)s * 64 + fo]; }
        float lo, hi;
        up2(u0.x, lo, hi); a[0] += lo; a[1] += hi;
        up2(u0.y, lo, hi); a[2] += lo; a[3] += hi;
        up2(u0.z, lo, hi); a[4] += lo; a[5] += hi;
        up2(u0.w, lo, hi); a[6] += lo; a[7] += hi;
        up2(u1.x, lo, hi); a[0] += lo; a[1] += hi;
        up2(u1.y, lo, hi); a[2] += lo; a[3] += hi;
        up2(u1.z, lo, hi); a[4] += lo; a[5] += hi;
        up2(u1.w, lo, hi); a[6] += lo; a[7] += hi;
    }
    #pragma unroll
    for (int off = 8; off <= 32; off <<= 1)
        #pragma unroll
        for (int k = 0; k < 8; ++k)
            a[k] += __shfl_xor(a[k], off);
    if (sub == 0) {
        uint4 o;
        o.x = (unsigned)f2bf(a[0]) | ((unsigned)f2bf(a[1]) << 16);
        o.y = (unsigned)f2bf(a[2]) | ((unsigned)f2bf(a[3]) << 16);
        o.z = (unsigned)f2bf(a[4]) | ((unsigned)f2bf(a[5]) << 16);
        o.w = (unsigned)f2bf(a[6]) | ((unsigned)f2bf(a[7]) << 16);
        *(uint4*)&fout[(size_t)node * 64 + fo] = o;
    }
}

// ---------------- 3rd hop fused with attention combine ----------------
// MODE 0: layer 1 (res from fp32 res buffer, apply ELU); MODE 1: layer 2.
template<int MODE>
__global__ __launch_bounds__(256)
void hop3_combine_kernel(const unsigned short* __restrict__ h0,
                         const unsigned short* __restrict__ f1,
                         const unsigned short* __restrict__ f2,
                         const float* __restrict__ res, const float* __restrict__ att,
                         const float* __restrict__ bias, float* __restrict__ out,
                         const int* __restrict__ rowptr, const int* __restrict__ col, int n)
{
    int node = blockIdx.x * 4 + (threadIdx.x >> 6);
    if (node >= n) return;
    int lane = threadIdx.x & 63;
    int sub = lane >> 3;
    int fo = (lane & 7) * 8;
    size_t base = (size_t)node * 64 + lane;

    // f3 = gather-sum of f2 rows (bf16, 8 lanes/edge)
    int beg = rowptr[node], end = rowptr[node + 1];
    int deg = end - beg;
    float a[8] = {};
    for (int b = 0; b < deg; b += 16) {
        int e0 = beg + b + sub, e1 = e0 + 8;
        uint4 u0 = make_uint4(0, 0, 0, 0), u1 = make_uint4(0, 0, 0, 0);
        if (e0 < end) { int s = col[e0]; u0 = *(const uint4*)&f2[(size_t)s * 64 + fo]; }
        if (e1 < end) { int s = col[e1]; u1 = *(const uint4*)&f2[(size_t)s * 64 + fo]; }
        float lo, hi;
        up2(u0.x, lo, hi); a[0] += lo; a[1] += hi;
        up2(u0.y, lo, hi); a[2] += lo; a[3] += hi;
        up2(u0.z, lo, hi); a[4] += lo; a[5] += hi;
        up2(u0.w, lo, hi); a[6] += lo; a[7] += hi;
        up2(u1.x, lo, hi); a[0] += lo; a[1] += hi;
        up2(u1.y, lo, hi); a[2] += lo; a[3] += hi;
        up2(u1.z, lo, hi); a[4] += lo; a[5] += hi;
        up2(u1.w, lo, hi); a[6] += lo; a[7] += hi;
    }
    #pragma unroll
    for (int off = 8; off <= 32; off <<= 1)
        #pragma unroll
        for (int k = 0; k < 8; ++k)
            a[k] += __shfl_xor(a[k], off);

    // redistribute to lane=feature: feature `lane` = component (lane&7) of
    // octet (lane>>3); octet q lives in lanes with (lane&7)==q.
    int q = lane >> 3;
    float c[8];
    #pragma unroll
    for (int k = 0; k < 8; ++k) c[k] = __shfl(a[k], q);
    int rs = lane & 7;
    float v3 = (rs == 0) ? c[0] : (rs == 1) ? c[1] : (rs == 2) ? c[2] :
               (rs == 3) ? c[3] : (rs == 4) ? c[4] : (rs == 5) ? c[5] :
               (rs == 6) ? c[6] : c[7];

    float v0 = bf2f(h0[base]), v1 = bf2f(f1[base]), v2 = bf2f(f2[base]);
    float alo = att[lane], ahi = att[64 + lane];

    float p0 = v0 * alo;
    float q0 = v0 * ahi;
    float q1 = v1 * ahi;
    float q2 = v2 * ahi;
    float q3 = v3 * ahi;
    #pragma unroll
    for (int off = 32; off > 0; off >>= 1) {
        p0 += __shfl_xor(p0, off);
        q0 += __shfl_xor(q0, off);
        q1 += __shfl_xor(q1, off);
        q2 += __shfl_xor(q2, off);
        q3 += __shfl_xor(q3, off);
    }
    float s0 = p0 + q0, s1 = p0 + q1, s2 = p0 + q2, s3 = p0 + q3;
    s0 = s0 > 0.f ? s0 : 0.2f * s0;
    s1 = s1 > 0.f ? s1 : 0.2f * s1;
    s2 = s2 > 0.f ? s2 : 0.2f * s2;
    s3 = s3 > 0.f ? s3 : 0.2f * s3;
    float m = fmaxf(fmaxf(s0, s1), fmaxf(s2, s3));
    float e0 = expf(s0 - m), e1 = expf(s1 - m), e2 = expf(s2 - m), e3 = expf(s3 - m);
    float inv = 1.f / (e0 + e1 + e2 + e3);
    float o = (e0 * v0 + e1 * v1 + e2 * v2 + e3 * v3) * inv;

    float r = (MODE == 0) ? res[base] : v0;
    o += r + bias[lane];
    if (MODE == 0) o = o > 0.f ? o : expm1f(o);
    out[base] = o;
}

extern "C" void kernel_launch(void* const* d_in, const int* in_sizes, int n_in,
                              void* d_out, int out_size, void* d_ws, size_t ws_size,
                              hipStream_t stream)
{
    const float* x     = (const float*)d_in[0];
    const int*   ei    = (const int*)  d_in[1];
    const float* W1    = (const float*)d_in[2];
    const float* att1  = (const float*)d_in[3];
    const float* bias1 = (const float*)d_in[4];
    const float* resW1 = (const float*)d_in[5];
    const float* W2    = (const float*)d_in[6];
    const float* att2  = (const float*)d_in[7];
    const float* bias2 = (const float*)d_in[8];

    const int N_ = in_sizes[0] / 128;
    const int E_ = in_sizes[1] / 2;
    const int* src = ei;
    const int* dst = ei + E_;

    float* out = (float*)d_out;
    size_t S = (size_t)N_ * 64;
    unsigned short* h0 = (unsigned short*)d_ws;          // S bf16
    unsigned short* f1 = h0 + S;                         // S bf16
    unsigned short* f2 = f1 + S;                         // S bf16
    int* rowptr = (int*)(f2 + S);        // N+1
    int* cnt    = rowptr + (N_ + 1);     // N
    int* excl   = cnt + N_;              // N
    int* bsum   = excl + N_;             // 256
    int* bofs   = bsum + 256;            // 256
    int* col    = bofs + 256;            // E

    const int NB    = (E_ + EPB - 1) / EPB;
    const int NBUCK = (N_ + 255) / 256;

    // aliases (consumed before f1/f2 are first written by the hops)
    unsigned int* packed = (unsigned int*)f1;            // E uints (fits: S*2B)
    int* table = (int*)(col + E_);                       // 256*NB
    int* exclT = table + 256 * NB;                       // 256*NB (+1 slack)
    int* bsumT = exclT + 256 * NB + 1;                   // 256
    int* bofsT = bsumT + 256;                            // 256

    dim3 blk(256);
    int grid_n    = (N_ + 63) / 64;
    int node_grid = (N_ + 3) / 4;
    int nb        = (N_ + 255) / 256;
    int nT        = 256 * NB;
    int nbT       = (nT + 255) / 256;                    // == NB

    // ---------------- CSR build ----------------
    part_hist_kernel<<<NB, blk, 0, stream>>>(dst, table, E_, NB);
    scanA_kernel<<<nbT, blk, 0, stream>>>(table, exclT, bsumT, nT);
    scanB_kernel<<<1, blk, 0, stream>>>(bsumT, bofsT, nbT);
    part_scatter_kernel<<<NB, blk, 0, stream>>>(src, dst, exclT, bofsT, packed, E_, NB);
    bucket_hist_kernel<<<NBUCK, blk, 0, stream>>>(packed, exclT, bofsT, cnt, E_, NB, N_);
    scanA_kernel<<<nb, blk, 0, stream>>>(cnt, excl, bsum, N_);
    scanB_kernel<<<1, blk, 0, stream>>>(bsum, bofs, nb);
    scanC_kernel<<<nb + 1, blk, 0, stream>>>(excl, bofs, rowptr, N_, E_);
    bucket_scatter_kernel<<<NBUCK, blk, 0, stream>>>(packed, exclT, bofsT, rowptr, col,
                                                     E_, NB, N_);

    // ---------------- layer 1 ----------------
    gemm64_kernel<128, 64><<<dim3(grid_n, 2), blk, 0, stream>>>(x, W1, resW1, h0, out, N_);
    hop_csr_kernel<<<node_grid, blk, 0, stream>>>(h0, f1, rowptr, col, N_);
    hop_csr_kernel<<<node_grid, blk, 0, stream>>>(f1, f2, rowptr, col, N_);
    hop3_combine_kernel<0><<<node_grid, blk, 0, stream>>>(h0, f1, f2, out, att1, bias1, out,
                                                          rowptr, col, N_);

    // ---------------- layer 2 ----------------
    gemm64_kernel<64, 64><<<dim3(grid_n, 1), blk, 0, stream>>>(out, W2, W2, h0, nullptr, N_);
    hop_csr_kernel<<<node_grid, blk, 0, stream>>>(h0, f1, rowptr, col, N_);
    hop_csr_kernel<<<node_grid, blk, 0, stream>>>(f1, f2, rowptr, col, N_);
    hop3_combine_kernel<1><<<node_grid, blk, 0, stream>>>(h0, f1, f2, nullptr, att2, bias2, out,
                                                          rowptr, col, N_);
}